// Round 1
// baseline (3255.610 us; speedup 1.0000x reference)
//
#include <hip/hip_runtime.h>
#include <math.h>

// Cobra forward, fp32 baseline.
// Shapes: B=4 T=1024 D=768 L=4 DI=1536 DS=64 NH=24 HD=64 DCONV=4
//         DPROJ=3224 CONVD=1664 HATT=8 EATT=96 CDIM=2048
// ws usage ~183 MB (all fp32 scratch).

#define EPSF 1e-5f

__device__ __forceinline__ float siluf(float x){ return x/(1.f+expf(-x)); }

// block=256 sum reduce; all 256 threads must call; result broadcast to all.
__device__ __forceinline__ float bsum256(float v, float* red){
  #pragma unroll
  for(int o2=32;o2;o2>>=1) v+=__shfl_down(v,o2,64);
  __syncthreads();
  if((threadIdx.x&63)==0) red[threadIdx.x>>6]=v;
  __syncthreads();
  return red[0]+red[1]+red[2]+red[3];
}

// ---------------- LayerNorm over 768, one row per block ----------------
__global__ __launch_bounds__(256) void k_ln768(const float* __restrict__ x,
    const float* __restrict__ g, const float* __restrict__ bb,
    float* __restrict__ o){
  int row=blockIdx.x, tid=threadIdx.x;
  const float* xr=x+(size_t)row*768;
  float v0=xr[tid], v1=xr[tid+256], v2=xr[tid+512];
  __shared__ float red[4];
  float m = bsum256(v0+v1+v2, red)*(1.f/768.f);
  float d0=v0-m,d1=v1-m,d2=v2-m;
  float var = bsum256(d0*d0+d1*d1+d2*d2, red)*(1.f/768.f);
  float rs=rsqrtf(var+EPSF);
  float* orow=o+(size_t)row*768;
  orow[tid]    =d0*rs*g[tid]    +bb[tid];
  orow[tid+256]=d1*rs*g[tid+256]+bb[tid+256];
  orow[tid+512]=d2*rs*g[tid+512]+bb[tid+512];
}

// ---------------- Double LayerNorm (enc then cob) ----------------
__global__ __launch_bounds__(256) void k_dblln(const float* __restrict__ x,
    const float* __restrict__ g1, const float* __restrict__ b1,
    const float* __restrict__ g2, const float* __restrict__ b2,
    float* __restrict__ o){
  int row=blockIdx.x, tid=threadIdx.x;
  const float* xr=x+(size_t)row*768;
  float v0=xr[tid], v1=xr[tid+256], v2=xr[tid+512];
  __shared__ float red[4];
  float m = bsum256(v0+v1+v2, red)*(1.f/768.f);
  float d0=v0-m,d1=v1-m,d2=v2-m;
  float var = bsum256(d0*d0+d1*d1+d2*d2, red)*(1.f/768.f);
  float rs=rsqrtf(var+EPSF);
  float x0=d0*rs*g1[tid]    +b1[tid];
  float x1=d1*rs*g1[tid+256]+b1[tid+256];
  float x2=d2*rs*g1[tid+512]+b1[tid+512];
  float m2 = bsum256(x0+x1+x2, red)*(1.f/768.f);
  float e0=x0-m2,e1=x1-m2,e2=x2-m2;
  float var2 = bsum256(e0*e0+e1*e1+e2*e2, red)*(1.f/768.f);
  float rs2=rsqrtf(var2+EPSF);
  float* orow=o+(size_t)row*768;
  orow[tid]    =e0*rs2*g2[tid]    +b2[tid];
  orow[tid+256]=e1*rs2*g2[tid+256]+b2[tid+256];
  orow[tid+512]=e2*rs2*g2[tid+512]+b2[tid+512];
}

// ---------------- GEMM: C[M,N] = act(A[M,K]@W[K,N] + bias) + res ----------------
// 128x128 tile, BK=16, 256 threads, 8x8 per thread. act: 0 none, 1 silu.
__global__ __launch_bounds__(256,2) void k_gemm(const float* __restrict__ A,
    const float* __restrict__ W, const float* __restrict__ bias,
    const float* __restrict__ res, float* __restrict__ C,
    int M, int N, int K, int act){
  __shared__ __align__(16) float As[16][132];
  __shared__ __align__(16) float Ws[16][132];
  int tid=threadIdx.x;
  int m0=blockIdx.x*128, n0=blockIdx.y*128;
  int ar=tid>>2, akq=tid&3;     // A staging: rows ar, ar+64; k-quad akq
  int wr=tid>>5, wq=tid&31;     // W staging: k-rows wr, wr+8; col-quad wq
  int ty=tid>>4, tx=tid&15;
  float acc[8][8];
  #pragma unroll
  for(int i=0;i<8;i++)
    #pragma unroll
    for(int j=0;j<8;j++) acc[i][j]=0.f;

  for(int k0=0;k0<K;k0+=16){
    float4 a0=*(const float4*)(A+(size_t)(m0+ar)*K+k0+akq*4);
    float4 a1=*(const float4*)(A+(size_t)(m0+ar+64)*K+k0+akq*4);
    int wc=n0+wq*4;
    float4 w0=make_float4(0.f,0.f,0.f,0.f), w1=w0;
    if(wc<N){
      w0=*(const float4*)(W+(size_t)(k0+wr)*N+wc);
      w1=*(const float4*)(W+(size_t)(k0+wr+8)*N+wc);
    }
    __syncthreads();
    As[akq*4+0][ar]=a0.x; As[akq*4+1][ar]=a0.y; As[akq*4+2][ar]=a0.z; As[akq*4+3][ar]=a0.w;
    As[akq*4+0][ar+64]=a1.x; As[akq*4+1][ar+64]=a1.y; As[akq*4+2][ar+64]=a1.z; As[akq*4+3][ar+64]=a1.w;
    *(float4*)&Ws[wr][wq*4]=w0;
    *(float4*)&Ws[wr+8][wq*4]=w1;
    __syncthreads();
    #pragma unroll
    for(int k=0;k<16;k++){
      float4 aL=*(const float4*)&As[k][ty*4];
      float4 aH=*(const float4*)&As[k][ty*4+64];
      float4 wL=*(const float4*)&Ws[k][tx*4];
      float4 wH=*(const float4*)&Ws[k][tx*4+64];
      float av[8]={aL.x,aL.y,aL.z,aL.w,aH.x,aH.y,aH.z,aH.w};
      float wv[8]={wL.x,wL.y,wL.z,wL.w,wH.x,wH.y,wH.z,wH.w};
      #pragma unroll
      for(int i=0;i<8;i++)
        #pragma unroll
        for(int j=0;j<8;j++)
          acc[i][j]=fmaf(av[i],wv[j],acc[i][j]);
    }
  }
  // epilogue
  #pragma unroll
  for(int i=0;i<8;i++){
    int row=m0 + ((i<4)? (ty*4+i) : (64+ty*4+i-4));
    #pragma unroll
    for(int jh=0;jh<2;jh++){
      int col=n0+tx*4+jh*64;
      if(col>=N) continue;
      float4 v;
      v.x=acc[i][jh*4+0]; v.y=acc[i][jh*4+1]; v.z=acc[i][jh*4+2]; v.w=acc[i][jh*4+3];
      if(bias){
        float4 bv=*(const float4*)(bias+col);
        v.x+=bv.x; v.y+=bv.y; v.z+=bv.z; v.w+=bv.w;
      }
      if(act==1){ v.x=siluf(v.x); v.y=siluf(v.y); v.z=siluf(v.z); v.w=siluf(v.w); }
      if(res){
        float4 rv=*(const float4*)(res+(size_t)row*N+col);
        v.x+=rv.x; v.y+=rv.y; v.z+=rv.z; v.w+=rv.w;
      }
      *(float4*)(C+(size_t)row*N+col)=v;
    }
  }
}

// ---------------- causal depthwise conv (width 4) + silu ----------------
// grid (ceil(1664/256), 8 t-chunks, 4 b), block 256
__global__ __launch_bounds__(256) void k_conv(const float* __restrict__ zx,
    const float* __restrict__ cw, const float* __restrict__ cb,
    float* __restrict__ xbc){
  int c=blockIdx.x*256+threadIdx.x;
  if(c>=1664) return;
  int t0=blockIdx.y*128, b=blockIdx.z;
  float4 w=*(const float4*)(cw+(size_t)c*4);
  float bias=cb[c];
  size_t inbase=((size_t)b*1024)*3224 + 1536 + c;
  float xm3=0.f,xm2=0.f,xm1=0.f;
  if(t0>0){
    xm3=zx[inbase+(size_t)(t0-3)*3224];
    xm2=zx[inbase+(size_t)(t0-2)*3224];
    xm1=zx[inbase+(size_t)(t0-1)*3224];
  }
  for(int i=0;i<128;i++){
    int t=t0+i;
    float xc=zx[inbase+(size_t)t*3224];
    float v=bias + w.x*xm3 + w.y*xm2 + w.z*xm1 + w.w*xc;
    xbc[((size_t)(b*1024+t))*1664 + c]=siluf(v);
    xm3=xm2; xm2=xm1; xm1=xc;
  }
}

// ---------------- dt = softplus(raw+bias), dA = exp(-exp(Alog)*dt) ----------------
__global__ __launch_bounds__(256) void k_dtdA(const float* __restrict__ zx,
    const float* __restrict__ dtb, const float* __restrict__ alog,
    float* __restrict__ dt_a, float* __restrict__ dA_a){
  int idx=blockIdx.x*256+threadIdx.x;
  if(idx>=98304) return;
  int row=idx/24, hh=idx-row*24;
  float v=zx[(size_t)row*3224+3200+hh]+dtb[hh];
  float dt=(v>20.f)? v : log1pf(expf(v));
  float dA=expf(-expf(alog[hh])*dt);
  dt_a[idx]=dt; dA_a[idx]=dA;
}

// ---------------- scan phase A: per-chunk local scan ----------------
// grid = ((b*24+h)*16 + c), 1536 blocks of 64 lanes; lane = p (head dim)
__global__ __launch_bounds__(64) void k_scanA(const float* __restrict__ xbc,
    const float* __restrict__ dt_a, const float* __restrict__ dA_a,
    float* __restrict__ y, float* __restrict__ Sloc, float* __restrict__ dpref){
  int blk=blockIdx.x;
  int c=blk&15, bh=blk>>4, h=bh%24, b=bh/24;
  int lane=threadIdx.x;
  float hs[64];
  #pragma unroll
  for(int n=0;n<64;n++) hs[n]=0.f;
  float pref=1.f;
  int tb=c*64;
  for(int t0=0;t0<64;t0++){
    int row=b*1024+tb+t0;
    const float* xr=xbc+(size_t)row*1664;
    float xv=xr[h*64+lane];
    float dtv=dt_a[row*24+h];
    float dAv=dA_a[row*24+h];
    float dtx=dtv*xv;
    const float* Bp=xr+1536;
    const float* Cp=xr+1600;
    float ya=0.f,yb=0.f,yc=0.f,yd=0.f;
    #pragma unroll
    for(int n=0;n<64;n+=4){
      float t0v=fmaf(dtx,Bp[n+0],hs[n+0]*dAv); hs[n+0]=t0v; ya=fmaf(t0v,Cp[n+0],ya);
      float t1v=fmaf(dtx,Bp[n+1],hs[n+1]*dAv); hs[n+1]=t1v; yb=fmaf(t1v,Cp[n+1],yb);
      float t2v=fmaf(dtx,Bp[n+2],hs[n+2]*dAv); hs[n+2]=t2v; yc=fmaf(t2v,Cp[n+2],yc);
      float t3v=fmaf(dtx,Bp[n+3],hs[n+3]*dAv); hs[n+3]=t3v; yd=fmaf(t3v,Cp[n+3],yd);
    }
    pref*=dAv;
    y[(size_t)row*1536 + h*64 + lane]=(ya+yb)+(yc+yd);
    if(lane==0) dpref[row*24+h]=pref;
  }
  float* sp=Sloc + ((size_t)blk*64 + lane)*64;
  #pragma unroll
  for(int n=0;n<64;n++) sp[n]=hs[n];
}

// ---------------- scan phase B: sequential combine over 16 chunks ----------------
// grid = 96 (b*24+h), block 256; thread owns 16 state elems
__global__ __launch_bounds__(256) void k_scanB(const float* __restrict__ Sloc,
    const float* __restrict__ dpref, float* __restrict__ Sin){
  int bh=blockIdx.x, tid=threadIdx.x;
  int b=bh/24, h=bh%24;
  float s[16];
  #pragma unroll
  for(int j=0;j<16;j++) s[j]=0.f;
  for(int c=0;c<16;c++){
    size_t base=((size_t)bh*16+c)*4096;
    #pragma unroll
    for(int j=0;j<16;j++) Sin[base + j*256 + tid]=s[j];
    float D=dpref[(size_t)(b*1024 + c*64 + 63)*24 + h];
    #pragma unroll
    for(int j=0;j<16;j++) s[j]=fmaf(s[j],D,Sloc[base + j*256 + tid]);
  }
}

// ---------------- scan phase C: add inter-chunk contribution + D*xh ----------------
__global__ __launch_bounds__(64) void k_scanC(const float* __restrict__ xbc,
    const float* __restrict__ Sin, const float* __restrict__ dpref,
    const float* __restrict__ Dp, float* __restrict__ y){
  int blk=blockIdx.x;
  int c=blk&15, bh=blk>>4, h=bh%24, b=bh/24;
  int lane=threadIdx.x;
  float s[64];
  const float* sp=Sin + ((size_t)blk*64 + lane)*64;
  #pragma unroll
  for(int n=0;n<64;n++) s[n]=sp[n];
  float dv=Dp[h];
  for(int t0=0;t0<64;t0++){
    int row=b*1024 + c*64 + t0;
    const float* xr=xbc+(size_t)row*1664;
    const float* Cp=xr+1600;
    float a0=0.f,a1=0.f,a2=0.f,a3=0.f;
    #pragma unroll
    for(int n=0;n<64;n+=4){
      a0=fmaf(s[n+0],Cp[n+0],a0);
      a1=fmaf(s[n+1],Cp[n+1],a1);
      a2=fmaf(s[n+2],Cp[n+2],a2);
      a3=fmaf(s[n+3],Cp[n+3],a3);
    }
    float dot=(a0+a1)+(a2+a3);
    float pref=dpref[row*24+h];
    float xv=xr[h*64+lane];
    size_t yi=(size_t)row*1536 + h*64 + lane;
    y[yi]=y[yi] + pref*dot + dv*xv;
  }
}

// ---------------- y = RMS(y * silu(z)) * w, in-place over 1536 ----------------
__global__ __launch_bounds__(256) void k_gaterms(float* __restrict__ y,
    const float* __restrict__ zx, const float* __restrict__ w){
  int row=blockIdx.x, tid=threadIdx.x;
  const float* zr=zx+(size_t)row*3224;
  float* yr=y+(size_t)row*1536;
  float v[6]; float ss=0.f;
  #pragma unroll
  for(int j=0;j<6;j++){
    int i=tid+j*256;
    float t=yr[i]*siluf(zr[i]);
    v[j]=t; ss+=t*t;
  }
  __shared__ float red[4];
  float tot=bsum256(ss,red);
  float sc=rsqrtf(tot*(1.f/1536.f)+EPSF);
  #pragma unroll
  for(int j=0;j<6;j++){
    int i=tid+j*256;
    yr[i]=v[j]*sc*w[i];
  }
}

// ---------------- attention head scores ----------------
// grid 512 (8 timesteps each), block 768: tid -> h=tid/96, f=tid%96
__global__ __launch_bounds__(768) void k_attn(const float* __restrict__ hatt,
    const float* __restrict__ wa, const float* __restrict__ ba,
    const float* __restrict__ wb, const float* __restrict__ bbv,
    const float* __restrict__ wc, const float* __restrict__ bc,
    float* __restrict__ score){
  __shared__ float hrow[8*768];
  __shared__ float red[768];
  __shared__ float rawv[8][8];
  int blk=blockIdx.x, tid=threadIdx.x;
  size_t base=(size_t)blk*8*768;
  for(int i=tid;i<6144;i+=768) hrow[i]=hatt[base+i];
  __syncthreads();
  int hh=tid/96, f=tid-hh*96;
  float aa[8], gg[8];
  float bav=ba[hh*96+f], bbx=bbv[hh*96+f];
  #pragma unroll
  for(int tt=0;tt<8;tt++){ aa[tt]=bav; gg[tt]=bbx; }
  const float* wap=wa + (size_t)hh*9216 + f;
  const float* wbp=wb + (size_t)hh*9216 + f;
  for(int e=0;e<96;e++){
    float wav=wap[(size_t)e*96];
    float wbw=wbp[(size_t)e*96];
    #pragma unroll
    for(int tt=0;tt<8;tt++){
      float hv=hrow[tt*768 + e*8 + hh];
      aa[tt]=fmaf(hv,wav,aa[tt]);
      gg[tt]=fmaf(hv,wbw,gg[tt]);
    }
  }
  float wcv=wc[hh*96+f];
  for(int tt=0;tt<8;tt++){
    float s=tanhf(aa[tt])*(1.f/(1.f+expf(-gg[tt])))*wcv;
    red[tid]=s;
    __syncthreads();
    if(tid<8){
      float sum=0.f;
      for(int i=0;i<96;i++) sum+=red[tid*96+i];
      rawv[tt][tid]=sum+bc[tid];
    }
    __syncthreads();
  }
  if(tid<8){
    float m=0.f;
    for(int h2=0;h2<8;h2++) m+=rawv[tid][h2];
    score[blk*8+tid]=m*(1.f/8.f);
  }
}

// ---------------- softmax over t per batch ----------------
__global__ __launch_bounds__(1024) void k_softmax(const float* __restrict__ score,
    float* __restrict__ A){
  int b=blockIdx.x, t=threadIdx.x, lane=t&63, w=t>>6;
  __shared__ float red[16]; __shared__ float bcast[1];
  float v=score[b*1024+t];
  float m=v;
  #pragma unroll
  for(int o=32;o;o>>=1) m=fmaxf(m,__shfl_down(m,o,64));
  if(!lane) red[w]=m;
  __syncthreads();
  if(t==0){ float mm=red[0]; for(int i=1;i<16;i++) mm=fmaxf(mm,red[i]); bcast[0]=mm; }
  __syncthreads();
  float M=bcast[0];
  float e=expf(v-M);
  float s=e;
  #pragma unroll
  for(int o=32;o;o>>=1) s+=__shfl_down(s,o,64);
  __syncthreads();
  if(!lane) red[w]=s;
  __syncthreads();
  if(t==0){ float ss=0.f; for(int i=0;i<16;i++) ss+=red[i]; bcast[0]=ss; }
  __syncthreads();
  A[b*1024+t]=e/bcast[0];
}

// ---------------- weighted pool partials ----------------
__global__ __launch_bounds__(256) void k_poolpart(const float* __restrict__ A,
    const float* __restrict__ x, float* __restrict__ part){
  int b=blockIdx.x, sl=blockIdx.y, tid=threadIdx.x;
  float a0=0.f,a1=0.f,a2=0.f;
  for(int i=0;i<128;i++){
    int t=sl*128+i;
    float a=A[b*1024+t];
    const float* xr=x+((size_t)(b*1024+t))*768;
    a0=fmaf(a,xr[tid],a0);
    a1=fmaf(a,xr[tid+256],a1);
    a2=fmaf(a,xr[tid+512],a2);
  }
  float* pp=part+((size_t)(b*8+sl))*768;
  pp[tid]=a0; pp[tid+256]=a1; pp[tid+512]=a2;
}

__global__ __launch_bounds__(256) void k_poolcomb(const float* __restrict__ part,
    float* __restrict__ pooled, float* __restrict__ dout_pooled){
  int b=blockIdx.x, tid=threadIdx.x;
  #pragma unroll
  for(int j=0;j<3;j++){
    int d=tid+j*256;
    float s=0.f;
    for(int sl=0;sl<8;sl++) s+=part[((size_t)(b*8+sl))*768+d];
    pooled[b*768+d]=s;
    dout_pooled[b*768+d]=s;
  }
}

// ---------------- small proj matmuls (K-split partials) ----------------
__global__ __launch_bounds__(256) void k_proj1(const float* __restrict__ pln,
    const float* __restrict__ w1, float* __restrict__ z1p){
  int n=blockIdx.x*256+threadIdx.x;
  int ks=blockIdx.y*96;
  float a0=0.f,a1=0.f,a2=0.f,a3=0.f;
  for(int k=ks;k<ks+96;k++){
    float wv=w1[(size_t)k*3072+n];
    a0=fmaf(pln[k],wv,a0);
    a1=fmaf(pln[768+k],wv,a1);
    a2=fmaf(pln[1536+k],wv,a2);
    a3=fmaf(pln[2304+k],wv,a3);
  }
  float* zp=z1p+(size_t)blockIdx.y*4*3072;
  zp[n]=a0; zp[3072+n]=a1; zp[6144+n]=a2; zp[9216+n]=a3;
}

__global__ __launch_bounds__(256) void k_comb1(const float* __restrict__ z1p,
    const float* __restrict__ b1, float* __restrict__ z1){
  int n=blockIdx.x*256+threadIdx.x;
  #pragma unroll
  for(int r=0;r<4;r++){
    float s=0.f;
    for(int ky=0;ky<8;ky++) s+=z1p[((size_t)ky*4+r)*3072+n];
    z1[(size_t)r*3072+n]=siluf(s+b1[n]);
  }
}

__global__ __launch_bounds__(256) void k_proj2(const float* __restrict__ z1,
    const float* __restrict__ w2, float* __restrict__ fp){
  int n=blockIdx.x*256+threadIdx.x;
  int ks=blockIdx.y*256;
  float a0=0.f,a1=0.f,a2=0.f,a3=0.f;
  for(int k=ks;k<ks+256;k++){
    float wv=w2[(size_t)k*2048+n];
    a0=fmaf(z1[k],wv,a0);
    a1=fmaf(z1[3072+k],wv,a1);
    a2=fmaf(z1[6144+k],wv,a2);
    a3=fmaf(z1[9216+k],wv,a3);
  }
  float* f=fp+(size_t)blockIdx.y*4*2048;
  f[n]=a0; f[2048+n]=a1; f[4096+n]=a2; f[6144+n]=a3;
}

__global__ __launch_bounds__(256) void k_comb2(const float* __restrict__ fp,
    const float* __restrict__ b2, const float* __restrict__ g,
    const float* __restrict__ bb, const float* __restrict__ mean,
    const float* __restrict__ var, float* __restrict__ out){
  int n=blockIdx.x*256+threadIdx.x;
  #pragma unroll
  for(int r=0;r<4;r++){
    float s=0.f;
    for(int ky=0;ky<12;ky++) s+=fp[((size_t)ky*4+r)*2048+n];
    s+=b2[n];
    out[(size_t)r*2048+n]=(s-mean[n])*rsqrtf(var[n]+EPSF)*g[n]+bb[n];
  }
}

// =======================================================================
extern "C" void kernel_launch(void* const* d_in, const int* in_sizes, int n_in,
                              void* d_out, int out_size, void* d_ws, size_t ws_size,
                              hipStream_t stream){
  (void)in_sizes; (void)n_in; (void)out_size; (void)ws_size;
  const float* x        =(const float*)d_in[0];
  const float* emb_ln_g =(const float*)d_in[1];
  const float* emb_ln_b =(const float*)d_in[2];
  const float* emb_w1   =(const float*)d_in[3];
  const float* emb_b1   =(const float*)d_in[4];
  const float* emb_w2   =(const float*)d_in[5];
  const float* emb_b2   =(const float*)d_in[6];
  const float* mam_ln_g =(const float*)d_in[7];
  const float* mam_ln_b =(const float*)d_in[8];
  const float* mam_in_w =(const float*)d_in[9];
  const float* mam_conv_w=(const float*)d_in[10];
  const float* mam_conv_b=(const float*)d_in[11];
  const float* mam_dt_bias=(const float*)d_in[12];
  const float* mam_A_log=(const float*)d_in[13];
  const float* mam_D    =(const float*)d_in[14];
  const float* mam_rms_w=(const float*)d_in[15];
  const float* mam_out_w=(const float*)d_in[16];
  const float* enc_ln_g =(const float*)d_in[17];
  const float* enc_ln_b =(const float*)d_in[18];
  const float* cob_ln_g =(const float*)d_in[19];
  const float* cob_ln_b =(const float*)d_in[20];
  const float* attn_wa  =(const float*)d_in[21];
  const float* attn_ba  =(const float*)d_in[22];
  const float* attn_wb  =(const float*)d_in[23];
  const float* attn_bb  =(const float*)d_in[24];
  const float* attn_wc  =(const float*)d_in[25];
  const float* attn_bc  =(const float*)d_in[26];
  const float* proj_ln_g=(const float*)d_in[27];
  const float* proj_ln_b=(const float*)d_in[28];
  const float* proj_w1  =(const float*)d_in[29];
  const float* proj_b1  =(const float*)d_in[30];
  const float* proj_w2  =(const float*)d_in[31];
  const float* proj_b2  =(const float*)d_in[32];
  const float* bn_g     =(const float*)d_in[33];
  const float* bn_b     =(const float*)d_in[34];
  const float* bn_mean  =(const float*)d_in[35];
  const float* bn_var   =(const float*)d_in[36];
  float* out=(float*)d_out;

  float* Wp=(float*)d_ws;
  size_t off=0;
  auto alloc=[&](size_t n){ float* p=Wp+off; off+=n; return p; };
  float* h    =alloc(3145728);   // 4096x768
  float* hn   =alloc(3145728);   // LN scratch
  float* zx   =alloc(13205504);  // 4096x3224
  float* xbc  =alloc(6815744);   // 4096x1664
  float* y    =alloc(6291456);   // 4096x1536 (also emb intermediate t1)
  float* Sloc =alloc(6291456);   // 96x16x64x64
  float* Sin  =alloc(6291456);
  float* dt_a =alloc(98304);
  float* dA_a =alloc(98304);
  float* dpref=alloc(98304);
  float* score=alloc(4096);
  float* Aw   =alloc(4096);
  float* part =alloc(24576);
  float* pooled=alloc(3072);
  float* pln  =alloc(3072);
  float* z1p  =alloc(98304);
  float* z1   =alloc(12288);
  float* fp   =alloc(98304);
  float* t1=y;

  // ---- embedding MLP ----
  k_ln768<<<4096,256,0,stream>>>(x, emb_ln_g, emb_ln_b, hn);
  k_gemm<<<dim3(32,6),256,0,stream>>>(hn, emb_w1, emb_b1, nullptr, t1, 4096,768,768, 1);
  k_gemm<<<dim3(32,6),256,0,stream>>>(t1, emb_w2, emb_b2, nullptr, h, 4096,768,768, 0);

  // ---- 4 mamba2 layers ----
  for(int l=0;l<4;l++){
    k_ln768<<<4096,256,0,stream>>>(h, mam_ln_g+(size_t)l*768, mam_ln_b+(size_t)l*768, hn);
    k_gemm<<<dim3(32,26),256,0,stream>>>(hn, mam_in_w+(size_t)l*768*3224, nullptr, nullptr, zx, 4096,3224,768, 0);
    k_conv<<<dim3(7,8,4),256,0,stream>>>(zx, mam_conv_w+(size_t)l*1664*4, mam_conv_b+(size_t)l*1664, xbc);
    k_dtdA<<<384,256,0,stream>>>(zx, mam_dt_bias+(size_t)l*24, mam_A_log+(size_t)l*24, dt_a, dA_a);
    k_scanA<<<1536,64,0,stream>>>(xbc, dt_a, dA_a, y, Sloc, dpref);
    k_scanB<<<96,256,0,stream>>>(Sloc, dpref, Sin);
    k_scanC<<<1536,64,0,stream>>>(xbc, Sin, dpref, mam_D+(size_t)l*24, y);
    k_gaterms<<<4096,256,0,stream>>>(y, zx, mam_rms_w+(size_t)l*1536);
    k_gemm<<<dim3(32,6),256,0,stream>>>(y, mam_out_w+(size_t)l*1536*768, nullptr, h, h, 4096,768,1536, 0);
  }

  // ---- head ----
  k_dblln<<<4096,256,0,stream>>>(h, enc_ln_g,enc_ln_b, cob_ln_g,cob_ln_b, hn);
  k_attn<<<512,768,0,stream>>>(hn, attn_wa,attn_ba,attn_wb,attn_bb,attn_wc,attn_bc, score);
  k_softmax<<<4,1024,0,stream>>>(score, Aw);
  k_poolpart<<<dim3(4,8),256,0,stream>>>(Aw, x, part);
  k_poolcomb<<<4,256,0,stream>>>(part, pooled, out+8192);
  k_ln768<<<4,256,0,stream>>>(pooled, proj_ln_g, proj_ln_b, pln);
  k_proj1<<<dim3(12,8),256,0,stream>>>(pln, proj_w1, z1p);
  k_comb1<<<12,256,0,stream>>>(z1p, proj_b1, z1);
  k_proj2<<<dim3(8,12),256,0,stream>>>(z1, proj_w2, fp);
  k_comb2<<<8,256,0,stream>>>(fp, proj_b2, bn_g, bn_b, bn_mean, bn_var, out);
}

// Round 11
// 2074.252 us; speedup vs baseline: 1.5695x; 1.5695x over previous
//
#include <hip/hip_runtime.h>
#include <math.h>

// Cobra forward. GEMMs via split-bf16 (hi+lo) MFMA: a*w ~= ah*wh + ah*wl + al*wh.
// Shapes: B=4 T=1024 D=768 L=4 DI=1536 DS=64 NH=24 HD=64 DCONV=4
//         DPROJ=3224 CONVD=1664 HATT=8 EATT=96 CDIM=2048

#define EPSF 1e-5f

typedef float f32x4 __attribute__((ext_vector_type(4)));
typedef short s16x8 __attribute__((ext_vector_type(8)));

__device__ __forceinline__ float siluf(float x){ return x/(1.f+expf(-x)); }

__device__ __forceinline__ float bsum256(float v, float* red){
  #pragma unroll
  for(int o2=32;o2;o2>>=1) v+=__shfl_down(v,o2,64);
  __syncthreads();
  if((threadIdx.x&63)==0) red[threadIdx.x>>6]=v;
  __syncthreads();
  return red[0]+red[1]+red[2]+red[3];
}

// truncation split: a = hi + rest, lo = bf16_trunc(rest). Exact hi, tiny lo error.
__device__ __forceinline__ void splitbf(float a, unsigned short& hi, unsigned short& lo){
  unsigned u=__float_as_uint(a);
  unsigned short h=(unsigned short)(u>>16);
  float hf=__uint_as_float((unsigned)h<<16);
  float l=a-hf;
  hi=h; lo=(unsigned short)(__float_as_uint(l)>>16);
}
__device__ __forceinline__ unsigned pack2(unsigned short a, unsigned short b){
  return (unsigned)a | ((unsigned)b<<16);
}

// ---------------- split-bf16 MFMA GEMM ----------------
// C[M,N] = act(A[M,K]@W[K,N] + bias) + res. 128x128 tile, BK=32, 256 thr = 4 waves,
// each wave a 64x64 block as 4x4 frags of 16x16. LDS rows padded to 40 shorts (80B).
__global__ __launch_bounds__(256,2) void k_gemm_mfma(const float* __restrict__ A,
    const float* __restrict__ W, const float* __restrict__ bias,
    const float* __restrict__ res, float* __restrict__ C,
    int M, int N, int K, int act){
  __shared__ __align__(16) unsigned short AhiL[128*40];
  __shared__ __align__(16) unsigned short AloL[128*40];
  __shared__ __align__(16) unsigned short WhiL[128*40];
  __shared__ __align__(16) unsigned short WloL[128*40];
  int tid=threadIdx.x;
  int m0=blockIdx.x*128, n0=blockIdx.y*128;
  int lane=tid&63, wid=tid>>6;
  int wr=(wid>>1)*64, wc=(wid&1)*64;
  int lr=lane&15, lkg=lane>>4;

  f32x4 acc[4][4];
  #pragma unroll
  for(int i=0;i<4;i++)
    #pragma unroll
    for(int j=0;j<4;j++) acc[i][j]=(f32x4)(0.f);

  int a_r=tid>>3;            // 0..31
  int a_k=(tid&7)*4;         // 0..28
  int w_n=tid&127;           // 0..127
  int w_kh=(tid>>7)*16;      // 0 or 16
  bool wvalid=(n0+w_n)<N;
  const float* Wcol=W+(size_t)(n0+w_n);

  for(int k0=0;k0<K;k0+=32){
    float4 av[4];
    #pragma unroll
    for(int q=0;q<4;q++)
      av[q]=*(const float4*)(A+(size_t)(m0+a_r+q*32)*K+k0+a_k);
    float wv[16];
    #pragma unroll
    for(int j=0;j<16;j++)
      wv[j]=wvalid? Wcol[(size_t)(k0+w_kh+j)*N] : 0.f;

    __syncthreads();
    #pragma unroll
    for(int q=0;q<4;q++){
      unsigned short h0,h1,h2,h3,l0,l1,l2,l3;
      splitbf(av[q].x,h0,l0); splitbf(av[q].y,h1,l1);
      splitbf(av[q].z,h2,l2); splitbf(av[q].w,h3,l3);
      uint2 hh; hh.x=pack2(h0,h1); hh.y=pack2(h2,h3);
      uint2 ll; ll.x=pack2(l0,l1); ll.y=pack2(l2,l3);
      int base=(a_r+q*32)*40+a_k;
      *(uint2*)&AhiL[base]=hh;
      *(uint2*)&AloL[base]=ll;
    }
    #pragma unroll
    for(int q=0;q<4;q++){
      unsigned short h0,h1,h2,h3,l0,l1,l2,l3;
      splitbf(wv[4*q+0],h0,l0); splitbf(wv[4*q+1],h1,l1);
      splitbf(wv[4*q+2],h2,l2); splitbf(wv[4*q+3],h3,l3);
      uint2 hh; hh.x=pack2(h0,h1); hh.y=pack2(h2,h3);
      uint2 ll; ll.x=pack2(l0,l1); ll.y=pack2(l2,l3);
      int base=w_n*40+w_kh+4*q;
      *(uint2*)&WhiL[base]=hh;
      *(uint2*)&WloL[base]=ll;
    }
    __syncthreads();

    s16x8 aH[4],aL[4],wH[4],wL[4];
    #pragma unroll
    for(int i=0;i<4;i++){
      int ab=(wr+i*16+lr)*40+lkg*8;
      aH[i]=*(const s16x8*)&AhiL[ab];
      aL[i]=*(const s16x8*)&AloL[ab];
      int wb=(wc+i*16+lr)*40+lkg*8;
      wH[i]=*(const s16x8*)&WhiL[wb];
      wL[i]=*(const s16x8*)&WloL[wb];
    }
    #pragma unroll
    for(int i=0;i<4;i++)
      #pragma unroll
      for(int j=0;j<4;j++)
        acc[i][j]=__builtin_amdgcn_mfma_f32_16x16x32_bf16(aH[i],wH[j],acc[i][j],0,0,0);
    #pragma unroll
    for(int i=0;i<4;i++)
      #pragma unroll
      for(int j=0;j<4;j++)
        acc[i][j]=__builtin_amdgcn_mfma_f32_16x16x32_bf16(aH[i],wL[j],acc[i][j],0,0,0);
    #pragma unroll
    for(int i=0;i<4;i++)
      #pragma unroll
      for(int j=0;j<4;j++)
        acc[i][j]=__builtin_amdgcn_mfma_f32_16x16x32_bf16(aL[i],wH[j],acc[i][j],0,0,0);
  }

  // epilogue: D row = m0+wr+i*16+lkg*4+r, col = n0+wc+j*16+lr
  #pragma unroll
  for(int i=0;i<4;i++){
    #pragma unroll
    for(int r=0;r<4;r++){
      int row=m0+wr+i*16+lkg*4+r;
      #pragma unroll
      for(int j=0;j<4;j++){
        int col=n0+wc+j*16+lr;
        if(col<N){
          float v=acc[i][j][r];
          if(bias) v+=bias[col];
          if(act==1) v=siluf(v);
          if(res) v+=res[(size_t)row*N+col];
          C[(size_t)row*N+col]=v;
        }
      }
    }
  }
}

// ---------------- LayerNorm over 768, one row per block ----------------
__global__ __launch_bounds__(256) void k_ln768(const float* __restrict__ x,
    const float* __restrict__ g, const float* __restrict__ bb,
    float* __restrict__ o){
  int row=blockIdx.x, tid=threadIdx.x;
  const float* xr=x+(size_t)row*768;
  float v0=xr[tid], v1=xr[tid+256], v2=xr[tid+512];
  __shared__ float red[4];
  float m = bsum256(v0+v1+v2, red)*(1.f/768.f);
  float d0=v0-m,d1=v1-m,d2=v2-m;
  float var = bsum256(d0*d0+d1*d1+d2*d2, red)*(1.f/768.f);
  float rs=rsqrtf(var+EPSF);
  float* orow=o+(size_t)row*768;
  orow[tid]    =d0*rs*g[tid]    +bb[tid];
  orow[tid+256]=d1*rs*g[tid+256]+bb[tid+256];
  orow[tid+512]=d2*rs*g[tid+512]+bb[tid+512];
}

// ---------------- Double LayerNorm (enc then cob) ----------------
__global__ __launch_bounds__(256) void k_dblln(const float* __restrict__ x,
    const float* __restrict__ g1, const float* __restrict__ b1,
    const float* __restrict__ g2, const float* __restrict__ b2,
    float* __restrict__ o){
  int row=blockIdx.x, tid=threadIdx.x;
  const float* xr=x+(size_t)row*768;
  float v0=xr[tid], v1=xr[tid+256], v2=xr[tid+512];
  __shared__ float red[4];
  float m = bsum256(v0+v1+v2, red)*(1.f/768.f);
  float d0=v0-m,d1=v1-m,d2=v2-m;
  float var = bsum256(d0*d0+d1*d1+d2*d2, red)*(1.f/768.f);
  float rs=rsqrtf(var+EPSF);
  float x0=d0*rs*g1[tid]    +b1[tid];
  float x1=d1*rs*g1[tid+256]+b1[tid+256];
  float x2=d2*rs*g1[tid+512]+b1[tid+512];
  float m2 = bsum256(x0+x1+x2, red)*(1.f/768.f);
  float e0=x0-m2,e1=x1-m2,e2=x2-m2;
  float var2 = bsum256(e0*e0+e1*e1+e2*e2, red)*(1.f/768.f);
  float rs2=rsqrtf(var2+EPSF);
  float* orow=o+(size_t)row*768;
  orow[tid]    =e0*rs2*g2[tid]    +b2[tid];
  orow[tid+256]=e1*rs2*g2[tid+256]+b2[tid+256];
  orow[tid+512]=e2*rs2*g2[tid+512]+b2[tid+512];
}

// ---------------- causal depthwise conv (width 4) + silu ----------------
__global__ __launch_bounds__(256) void k_conv(const float* __restrict__ zx,
    const float* __restrict__ cw, const float* __restrict__ cb,
    float* __restrict__ xbc){
  int c=blockIdx.x*256+threadIdx.x;
  if(c>=1664) return;
  int t0=blockIdx.y*128, b=blockIdx.z;
  float4 w=*(const float4*)(cw+(size_t)c*4);
  float bias=cb[c];
  size_t inbase=((size_t)b*1024)*3224 + 1536 + c;
  float xm3=0.f,xm2=0.f,xm1=0.f;
  if(t0>0){
    xm3=zx[inbase+(size_t)(t0-3)*3224];
    xm2=zx[inbase+(size_t)(t0-2)*3224];
    xm1=zx[inbase+(size_t)(t0-1)*3224];
  }
  for(int i=0;i<128;i++){
    int t=t0+i;
    float xc=zx[inbase+(size_t)t*3224];
    float v=bias + w.x*xm3 + w.y*xm2 + w.z*xm1 + w.w*xc;
    xbc[((size_t)(b*1024+t))*1664 + c]=siluf(v);
    xm3=xm2; xm2=xm1; xm1=xc;
  }
}

// ---------------- dt/dA ----------------
__global__ __launch_bounds__(256) void k_dtdA(const float* __restrict__ zx,
    const float* __restrict__ dtb, const float* __restrict__ alog,
    float* __restrict__ dt_a, float* __restrict__ dA_a){
  int idx=blockIdx.x*256+threadIdx.x;
  if(idx>=98304) return;
  int row=idx/24, hh=idx-row*24;
  float v=zx[(size_t)row*3224+3200+hh]+dtb[hh];
  float dt=(v>20.f)? v : log1pf(expf(v));
  float dA=expf(-expf(alog[hh])*dt);
  dt_a[idx]=dt; dA_a[idx]=dA;
}

// ---------------- scan phase A ----------------
__global__ __launch_bounds__(64) void k_scanA(const float* __restrict__ xbc,
    const float* __restrict__ dt_a, const float* __restrict__ dA_a,
    float* __restrict__ y, float* __restrict__ Sloc, float* __restrict__ dpref){
  int blk=blockIdx.x;
  int c=blk&15, bh=blk>>4, h=bh%24, b=bh/24;
  int lane=threadIdx.x;
  float hs[64];
  #pragma unroll
  for(int n=0;n<64;n++) hs[n]=0.f;
  float pref=1.f;
  int tb=c*64;
  for(int t0=0;t0<64;t0++){
    int row=b*1024+tb+t0;
    const float* xr=xbc+(size_t)row*1664;
    float xv=xr[h*64+lane];
    float dtv=dt_a[row*24+h];
    float dAv=dA_a[row*24+h];
    float dtx=dtv*xv;
    const float* Bp=xr+1536;
    const float* Cp=xr+1600;
    float ya=0.f,yb=0.f,yc=0.f,yd=0.f;
    #pragma unroll
    for(int n=0;n<64;n+=4){
      float t0v=fmaf(dtx,Bp[n+0],hs[n+0]*dAv); hs[n+0]=t0v; ya=fmaf(t0v,Cp[n+0],ya);
      float t1v=fmaf(dtx,Bp[n+1],hs[n+1]*dAv); hs[n+1]=t1v; yb=fmaf(t1v,Cp[n+1],yb);
      float t2v=fmaf(dtx,Bp[n+2],hs[n+2]*dAv); hs[n+2]=t2v; yc=fmaf(t2v,Cp[n+2],yc);
      float t3v=fmaf(dtx,Bp[n+3],hs[n+3]*dAv); hs[n+3]=t3v; yd=fmaf(t3v,Cp[n+3],yd);
    }
    pref*=dAv;
    y[(size_t)row*1536 + h*64 + lane]=(ya+yb)+(yc+yd);
    if(lane==0) dpref[row*24+h]=pref;
  }
  float* sp=Sloc + ((size_t)blk*64 + lane)*64;
  #pragma unroll
  for(int n=0;n<64;n++) sp[n]=hs[n];
}

// ---------------- scan phase B ----------------
__global__ __launch_bounds__(256) void k_scanB(const float* __restrict__ Sloc,
    const float* __restrict__ dpref, float* __restrict__ Sin){
  int bh=blockIdx.x, tid=threadIdx.x;
  int b=bh/24, h=bh%24;
  float s[16];
  #pragma unroll
  for(int j=0;j<16;j++) s[j]=0.f;
  for(int c=0;c<16;c++){
    size_t base=((size_t)bh*16+c)*4096;
    #pragma unroll
    for(int j=0;j<16;j++) Sin[base + j*256 + tid]=s[j];
    float D=dpref[(size_t)(b*1024 + c*64 + 63)*24 + h];
    #pragma unroll
    for(int j=0;j<16;j++) s[j]=fmaf(s[j],D,Sloc[base + j*256 + tid]);
  }
}

// ---------------- scan phase C ----------------
__global__ __launch_bounds__(64) void k_scanC(const float* __restrict__ xbc,
    const float* __restrict__ Sin, const float* __restrict__ dpref,
    const float* __restrict__ Dp, float* __restrict__ y){
  int blk=blockIdx.x;
  int c=blk&15, bh=blk>>4, h=bh%24, b=bh/24;
  int lane=threadIdx.x;
  float s[64];
  const float* sp=Sin + ((size_t)blk*64 + lane)*64;
  #pragma unroll
  for(int n=0;n<64;n++) s[n]=sp[n];
  float dv=Dp[h];
  for(int t0=0;t0<64;t0++){
    int row=b*1024 + c*64 + t0;
    const float* xr=xbc+(size_t)row*1664;
    const float* Cp=xr+1600;
    float a0=0.f,a1=0.f,a2=0.f,a3=0.f;
    #pragma unroll
    for(int n=0;n<64;n+=4){
      a0=fmaf(s[n+0],Cp[n+0],a0);
      a1=fmaf(s[n+1],Cp[n+1],a1);
      a2=fmaf(s[n+2],Cp[n+2],a2);
      a3=fmaf(s[n+3],Cp[n+3],a3);
    }
    float dot=(a0+a1)+(a2+a3);
    float pref=dpref[row*24+h];
    float xv=xr[h*64+lane];
    size_t yi=(size_t)row*1536 + h*64 + lane;
    y[yi]=y[yi] + pref*dot + dv*xv;
  }
}

// ---------------- gate + RMS ----------------
__global__ __launch_bounds__(256) void k_gaterms(float* __restrict__ y,
    const float* __restrict__ zx, const float* __restrict__ w){
  int row=blockIdx.x, tid=threadIdx.x;
  const float* zr=zx+(size_t)row*3224;
  float* yr=y+(size_t)row*1536;
  float v[6]; float ss=0.f;
  #pragma unroll
  for(int j=0;j<6;j++){
    int i=tid+j*256;
    float t=yr[i]*siluf(zr[i]);
    v[j]=t; ss+=t*t;
  }
  __shared__ float red[4];
  float tot=bsum256(ss,red);
  float sc=rsqrtf(tot*(1.f/1536.f)+EPSF);
  #pragma unroll
  for(int j=0;j<6;j++){
    int i=tid+j*256;
    yr[i]=v[j]*sc*w[i];
  }
}

// ---------------- attention head scores ----------------
__global__ __launch_bounds__(768) void k_attn(const float* __restrict__ hatt,
    const float* __restrict__ wa, const float* __restrict__ ba,
    const float* __restrict__ wb, const float* __restrict__ bbv,
    const float* __restrict__ wc, const float* __restrict__ bc,
    float* __restrict__ score){
  __shared__ float hrow[8*768];
  __shared__ float red[768];
  __shared__ float rawv[8][8];
  int blk=blockIdx.x, tid=threadIdx.x;
  size_t base=(size_t)blk*8*768;
  for(int i=tid;i<6144;i+=768) hrow[i]=hatt[base+i];
  __syncthreads();
  int hh=tid/96, f=tid-hh*96;
  float aa[8], gg[8];
  float bav=ba[hh*96+f], bbx=bbv[hh*96+f];
  #pragma unroll
  for(int tt=0;tt<8;tt++){ aa[tt]=bav; gg[tt]=bbx; }
  const float* wap=wa + (size_t)hh*9216 + f;
  const float* wbp=wb + (size_t)hh*9216 + f;
  for(int e=0;e<96;e++){
    float wav=wap[(size_t)e*96];
    float wbw=wbp[(size_t)e*96];
    #pragma unroll
    for(int tt=0;tt<8;tt++){
      float hv=hrow[tt*768 + e*8 + hh];
      aa[tt]=fmaf(hv,wav,aa[tt]);
      gg[tt]=fmaf(hv,wbw,gg[tt]);
    }
  }
  float wcv=wc[hh*96+f];
  for(int tt=0;tt<8;tt++){
    float s=tanhf(aa[tt])*(1.f/(1.f+expf(-gg[tt])))*wcv;
    red[tid]=s;
    __syncthreads();
    if(tid<8){
      float sum=0.f;
      for(int i=0;i<96;i++) sum+=red[tid*96+i];
      rawv[tt][tid]=sum+bc[tid];
    }
    __syncthreads();
  }
  if(tid<8){
    float m=0.f;
    for(int h2=0;h2<8;h2++) m+=rawv[tid][h2];
    score[blk*8+tid]=m*(1.f/8.f);
  }
}

// ---------------- softmax over t per batch ----------------
__global__ __launch_bounds__(1024) void k_softmax(const float* __restrict__ score,
    float* __restrict__ A){
  int b=blockIdx.x, t=threadIdx.x, lane=t&63, w=t>>6;
  __shared__ float red[16]; __shared__ float bcast[1];
  float v=score[b*1024+t];
  float m=v;
  #pragma unroll
  for(int o=32;o;o>>=1) m=fmaxf(m,__shfl_down(m,o,64));
  if(!lane) red[w]=m;
  __syncthreads();
  if(t==0){ float mm=red[0]; for(int i=1;i<16;i++) mm=fmaxf(mm,red[i]); bcast[0]=mm; }
  __syncthreads();
  float M=bcast[0];
  float e=expf(v-M);
  float s=e;
  #pragma unroll
  for(int o=32;o;o>>=1) s+=__shfl_down(s,o,64);
  __syncthreads();
  if(!lane) red[w]=s;
  __syncthreads();
  if(t==0){ float ss=0.f; for(int i=0;i<16;i++) ss+=red[i]; bcast[0]=ss; }
  __syncthreads();
  A[b*1024+t]=e/bcast[0];
}

// ---------------- weighted pool ----------------
__global__ __launch_bounds__(256) void k_poolpart(const float* __restrict__ A,
    const float* __restrict__ x, float* __restrict__ part){
  int b=blockIdx.x, sl=blockIdx.y, tid=threadIdx.x;
  float a0=0.f,a1=0.f,a2=0.f;
  for(int i=0;i<128;i++){
    int t=sl*128+i;
    float a=A[b*1024+t];
    const float* xr=x+((size_t)(b*1024+t))*768;
    a0=fmaf(a,xr[tid],a0);
    a1=fmaf(a,xr[tid+256],a1);
    a2=fmaf(a,xr[tid+512],a2);
  }
  float* pp=part+((size_t)(b*8+sl))*768;
  pp[tid]=a0; pp[tid+256]=a1; pp[tid+512]=a2;
}

__global__ __launch_bounds__(256) void k_poolcomb(const float* __restrict__ part,
    float* __restrict__ pooled, float* __restrict__ dout_pooled){
  int b=blockIdx.x, tid=threadIdx.x;
  #pragma unroll
  for(int j=0;j<3;j++){
    int d=tid+j*256;
    float s=0.f;
    for(int sl=0;sl<8;sl++) s+=part[((size_t)(b*8+sl))*768+d];
    pooled[b*768+d]=s;
    dout_pooled[b*768+d]=s;
  }
}

// ---------------- small proj matmuls ----------------
__global__ __launch_bounds__(256) void k_proj1(const float* __restrict__ pln,
    const float* __restrict__ w1, float* __restrict__ z1p){
  int n=blockIdx.x*256+threadIdx.x;
  int ks=blockIdx.y*96;
  float a0=0.f,a1=0.f,a2=0.f,a3=0.f;
  for(int k=ks;k<ks+96;k++){
    float wv=w1[(size_t)k*3072+n];
    a0=fmaf(pln[k],wv,a0);
    a1=fmaf(pln[768+k],wv,a1);
    a2=fmaf(pln[1536+k],wv,a2);
    a3=fmaf(pln[2304+k],wv,a3);
  }
  float* zp=z1p+(size_t)blockIdx.y*4*3072;
  zp[n]=a0; zp[3072+n]=a1; zp[6144+n]=a2; zp[9216+n]=a3;
}

__global__ __launch_bounds__(256) void k_comb1(const float* __restrict__ z1p,
    const float* __restrict__ b1, float* __restrict__ z1){
  int n=blockIdx.x*256+threadIdx.x;
  #pragma unroll
  for(int r=0;r<4;r++){
    float s=0.f;
    for(int ky=0;ky<8;ky++) s+=z1p[((size_t)ky*4+r)*3072+n];
    z1[(size_t)r*3072+n]=siluf(s+b1[n]);
  }
}

__global__ __launch_bounds__(256) void k_proj2(const float* __restrict__ z1,
    const float* __restrict__ w2, float* __restrict__ fp){
  int n=blockIdx.x*256+threadIdx.x;
  int ks=blockIdx.y*256;
  float a0=0.f,a1=0.f,a2=0.f,a3=0.f;
  for(int k=ks;k<ks+256;k++){
    float wv=w2[(size_t)k*2048+n];
    a0=fmaf(z1[k],wv,a0);
    a1=fmaf(z1[3072+k],wv,a1);
    a2=fmaf(z1[6144+k],wv,a2);
    a3=fmaf(z1[9216+k],wv,a3);
  }
  float* f=fp+(size_t)blockIdx.y*4*2048;
  f[n]=a0; f[2048+n]=a1; f[4096+n]=a2; f[6144+n]=a3;
}

__global__ __launch_bounds__(256) void k_comb2(const float* __restrict__ fp,
    const float* __restrict__ b2, const float* __restrict__ g,
    const float* __restrict__ bb, const float* __restrict__ mean,
    const float* __restrict__ var, float* __restrict__ out){
  int n=blockIdx.x*256+threadIdx.x;
  #pragma unroll
  for(int r=0;r<4;r++){
    float s=0.f;
    for(int ky=0;ky<12;ky++) s+=fp[((size_t)ky*4+r)*2048+n];
    s+=b2[n];
    out[(size_t)r*2048+n]=(s-mean[n])*rsqrtf(var[n]+EPSF)*g[n]+bb[n];
  }
}

// =======================================================================
extern "C" void kernel_launch(void* const* d_in, const int* in_sizes, int n_in,
                              void* d_out, int out_size, void* d_ws, size_t ws_size,
                              hipStream_t stream){
  (void)in_sizes; (void)n_in; (void)out_size; (void)ws_size;
  const float* x        =(const float*)d_in[0];
  const float* emb_ln_g =(const float*)d_in[1];
  const float* emb_ln_b =(const float*)d_in[2];
  const float* emb_w1   =(const float*)d_in[3];
  const float* emb_b1   =(const float*)d_in[4];
  const float* emb_w2   =(const float*)d_in[5];
  const float* emb_b2   =(const float*)d_in[6];
  const float* mam_ln_g =(const float*)d_in[7];
  const float* mam_ln_b =(const float*)d_in[8];
  const float* mam_in_w =(const float*)d_in[9];
  const float* mam_conv_w=(const float*)d_in[10];
  const float* mam_conv_b=(const float*)d_in[11];
  const float* mam_dt_bias=(const float*)d_in[12];
  const float* mam_A_log=(const float*)d_in[13];
  const float* mam_D    =(const float*)d_in[14];
  const float* mam_rms_w=(const float*)d_in[15];
  const float* mam_out_w=(const float*)d_in[16];
  const float* enc_ln_g =(const float*)d_in[17];
  const float* enc_ln_b =(const float*)d_in[18];
  const float* cob_ln_g =(const float*)d_in[19];
  const float* cob_ln_b =(const float*)d_in[20];
  const float* attn_wa  =(const float*)d_in[21];
  const float* attn_ba  =(const float*)d_in[22];
  const float* attn_wb  =(const float*)d_in[23];
  const float* attn_bb  =(const float*)d_in[24];
  const float* attn_wc  =(const float*)d_in[25];
  const float* attn_bc  =(const float*)d_in[26];
  const float* proj_ln_g=(const float*)d_in[27];
  const float* proj_ln_b=(const float*)d_in[28];
  const float* proj_w1  =(const float*)d_in[29];
  const float* proj_b1  =(const float*)d_in[30];
  const float* proj_w2  =(const float*)d_in[31];
  const float* proj_b2  =(const float*)d_in[32];
  const float* bn_g     =(const float*)d_in[33];
  const float* bn_b     =(const float*)d_in[34];
  const float* bn_mean  =(const float*)d_in[35];
  const float* bn_var   =(const float*)d_in[36];
  float* out=(float*)d_out;

  float* Wp=(float*)d_ws;
  size_t off=0;
  auto alloc=[&](size_t n){ float* p=Wp+off; off+=n; return p; };
  float* h    =alloc(3145728);   // 4096x768
  float* hn   =alloc(3145728);
  float* zx   =alloc(13205504);  // 4096x3224
  float* xbc  =alloc(6815744);   // 4096x1664
  float* y    =alloc(6291456);   // 4096x1536
  float* Sloc =alloc(6291456);
  float* Sin  =alloc(6291456);
  float* dt_a =alloc(98304);
  float* dA_a =alloc(98304);
  float* dpref=alloc(98304);
  float* score=alloc(4096);
  float* Aw   =alloc(4096);
  float* part =alloc(24576);
  float* pooled=alloc(3072);
  float* pln  =alloc(3072);
  float* z1p  =alloc(98304);
  float* z1   =alloc(12288);
  float* fp   =alloc(98304);
  float* t1=y;

  // ---- embedding MLP ----
  k_ln768<<<4096,256,0,stream>>>(x, emb_ln_g, emb_ln_b, hn);
  k_gemm_mfma<<<dim3(32,6),256,0,stream>>>(hn, emb_w1, emb_b1, nullptr, t1, 4096,768,768, 1);
  k_gemm_mfma<<<dim3(32,6),256,0,stream>>>(t1, emb_w2, emb_b2, nullptr, h, 4096,768,768, 0);

  // ---- 4 mamba2 layers ----
  for(int l=0;l<4;l++){
    k_ln768<<<4096,256,0,stream>>>(h, mam_ln_g+(size_t)l*768, mam_ln_b+(size_t)l*768, hn);
    k_gemm_mfma<<<dim3(32,26),256,0,stream>>>(hn, mam_in_w+(size_t)l*768*3224, nullptr, nullptr, zx, 4096,3224,768, 0);
    k_conv<<<dim3(7,8,4),256,0,stream>>>(zx, mam_conv_w+(size_t)l*1664*4, mam_conv_b+(size_t)l*1664, xbc);
    k_dtdA<<<384,256,0,stream>>>(zx, mam_dt_bias+(size_t)l*24, mam_A_log+(size_t)l*24, dt_a, dA_a);
    k_scanA<<<1536,64,0,stream>>>(xbc, dt_a, dA_a, y, Sloc, dpref);
    k_scanB<<<96,256,0,stream>>>(Sloc, dpref, Sin);
    k_scanC<<<1536,64,0,stream>>>(xbc, Sin, dpref, mam_D+(size_t)l*24, y);
    k_gaterms<<<4096,256,0,stream>>>(y, zx, mam_rms_w+(size_t)l*1536);
    k_gemm_mfma<<<dim3(32,6),256,0,stream>>>(y, mam_out_w+(size_t)l*1536*768, nullptr, h, h, 4096,768,1536, 0);
  }

  // ---- head ----
  k_dblln<<<4096,256,0,stream>>>(h, enc_ln_g,enc_ln_b, cob_ln_g,cob_ln_b, hn);
  k_attn<<<512,768,0,stream>>>(hn, attn_wa,attn_ba,attn_wb,attn_bb,attn_wc,attn_bc, score);
  k_softmax<<<4,1024,0,stream>>>(score, Aw);
  k_poolpart<<<dim3(4,8),256,0,stream>>>(Aw, x, part);
  k_poolcomb<<<4,256,0,stream>>>(part, pooled, out+8192);
  k_ln768<<<4,256,0,stream>>>(pooled, proj_ln_g, proj_ln_b, pln);
  k_proj1<<<dim3(12,8),256,0,stream>>>(pln, proj_w1, z1p);
  k_comb1<<<12,256,0,stream>>>(z1p, proj_b1, z1);
  k_proj2<<<dim3(8,12),256,0,stream>>>(z1, proj_w2, fp);
  k_comb2<<<8,256,0,stream>>>(fp, proj_b2, bn_g, bn_b, bn_mean, bn_var, out);
}

// Round 12
// 1808.239 us; speedup vs baseline: 1.8004x; 1.1471x over previous
//
#include <hip/hip_runtime.h>
#include <math.h>

// Cobra forward. GEMMs: pre-split fp32 -> bf16 hi/lo in fragment-preorder, then
// MFMA GEMM with global_load_lds staging (zero staging VALU, zero LDS bank
// conflicts). a*w ~= ah*wh + ah*wl + al*wh (exact-hi truncation split).
// Shapes: B=4 T=1024 D=768 L=4 DI=1536 DPROJ=3224 CONVD=1664

#define EPSF 1e-5f

typedef float f32x4 __attribute__((ext_vector_type(4)));
typedef short s16x8 __attribute__((ext_vector_type(8)));

__device__ __forceinline__ float siluf(float x){ return x/(1.f+expf(-x)); }

__device__ __forceinline__ float bsum256(float v, float* red){
  #pragma unroll
  for(int o2=32;o2;o2>>=1) v+=__shfl_down(v,o2,64);
  __syncthreads();
  if((threadIdx.x&63)==0) red[threadIdx.x>>6]=v;
  __syncthreads();
  return red[0]+red[1]+red[2]+red[3];
}

// truncation split: hi = bf16_trunc(a) (exact top bits), lo = bf16_trunc(a - hi)
__device__ __forceinline__ void split1(float a, short& h, short& l){
  unsigned u=__float_as_uint(a);
  unsigned short hi=(unsigned short)(u>>16);
  float rest=a-__uint_as_float((unsigned)hi<<16);
  h=(short)hi;
  l=(short)(unsigned short)(__float_as_uint(rest)>>16);
}

// async global->LDS, 16B per lane; LDS dest is wave-uniform base + lane*16.
__device__ __forceinline__ void gload16(const void* g, void* l){
  __builtin_amdgcn_global_load_lds((const __attribute__((address_space(1))) void*)g,
                                   (__attribute__((address_space(3))) void*)l, 16, 0, 0);
}

// ---------------- split A (fp32 [M][K]) -> Ah/Al bf16, fragment-preordered ----
// layout (shorts): ((mt*Kt+kt)*4096) + rb*512 + lkg*128 + lr*8 + e
//   where row m = mt*128+rb*16+lr, k = kt*32+lkg*8+e. Exact-grid: M*K/8 threads.
__global__ __launch_bounds__(256) void k_splitA(const float* __restrict__ A,
    unsigned short* __restrict__ Ah, unsigned short* __restrict__ Al,
    int K, int Kt){
  int g=blockIdx.x*256+threadIdx.x;
  int lr=g&15, lkg=(g>>4)&3, rb=(g>>6)&7, seg=g>>9;
  int kt=seg%Kt, mt=seg/Kt;
  int m=mt*128+rb*16+lr;
  int k0=kt*32+lkg*8;
  float4 f0=*(const float4*)(A+(size_t)m*K+k0);
  float4 f1=*(const float4*)(A+(size_t)m*K+k0+4);
  float v[8]={f0.x,f0.y,f0.z,f0.w,f1.x,f1.y,f1.z,f1.w};
  s16x8 h,l;
  #pragma unroll
  for(int i=0;i<8;i++){ short hh,ll; split1(v[i],hh,ll); h[i]=hh; l[i]=ll; }
  *(s16x8*)(Ah+(size_t)g*8)=h;
  *(s16x8*)(Al+(size_t)g*8)=l;
}

// ---------------- split W (fp32 [K][N]) -> Wh/Wl bf16, col-tiled + transposed --
// layout (shorts): ((nt*Kt+kt)*4096) + jb*512 + lkg*128 + lr*8 + e
//   where col n = nt*128+jb*16+lr, k = kt*32+lkg*8+e. Zero-pads n>=N.
__global__ __launch_bounds__(256) void k_splitW(const float* __restrict__ W,
    unsigned short* __restrict__ Wh, unsigned short* __restrict__ Wl,
    int N, int Kt){
  int g=blockIdx.x*256+threadIdx.x;
  int lr=g&15, lkg=(g>>4)&3, jb=(g>>6)&7, seg=g>>9;
  int kt=seg%Kt, nt=seg/Kt;
  int n=nt*128+jb*16+lr;
  int k0=kt*32+lkg*8;
  s16x8 h,l;
  if(n<N){
    #pragma unroll
    for(int e=0;e<8;e++){
      float v=W[(size_t)(k0+e)*N+n];
      short hh,ll; split1(v,hh,ll); h[e]=hh; l[e]=ll;
    }
  }else{
    #pragma unroll
    for(int e=0;e<8;e++){ h[e]=0; l[e]=0; }
  }
  *(s16x8*)(Wh+(size_t)g*8)=h;
  *(s16x8*)(Wl+(size_t)g*8)=l;
}

// ---------------- MFMA GEMM on pre-split fragments ----------------
// C[M,N'=gridDim.y*128 padded] = act(A@W + bias) + res, true-N guarded.
// 128x128 tile, BK=32, 4 waves, wave block 64x64 as 4x4 16x16x32 frags.
// LDS: 4 x 8KB linear segments (Ah,Al,Wh,Wl per K-step); staging via
// global_load_lds (linear), frag reads = contiguous 1KB/wave (0 conflicts).
__global__ __launch_bounds__(256,3) void k_gemm2(const unsigned short* __restrict__ Ah,
    const unsigned short* __restrict__ Al, const unsigned short* __restrict__ Wh,
    const unsigned short* __restrict__ Wl, const float* __restrict__ bias,
    const float* __restrict__ res, float* __restrict__ C,
    int N, int Kt, int act){
  __shared__ __align__(16) unsigned short sm[16384]; // 32KB
  int tid=threadIdx.x, lane=tid&63, wid=tid>>6;
  int mt=blockIdx.x, nt=blockIdx.y;
  int lr=lane&15, lkg=lane>>4;
  int wr=(wid>>1)*64, wc=(wid&1)*64;

  f32x4 acc[4][4];
  #pragma unroll
  for(int i=0;i<4;i++)
    #pragma unroll
    for(int j=0;j<4;j++) acc[i][j]=(f32x4)(0.f);

  size_t aseg=(size_t)mt*Kt*4096;
  size_t wseg=(size_t)nt*Kt*4096;
  int so=wid*512+lane*8;   // src offset within segment (shorts)
  int lo=wid*512;          // lds wave-uniform offset (shorts)
  int ab=(wid>>1)*2048+lane*8;   // A frag base (shorts)
  int wb=(wid&1)*2048+lane*8;    // W frag base (shorts)

  for(int kt=0;kt<Kt;++kt){
    const unsigned short* ga=Ah+aseg+(size_t)kt*4096;
    const unsigned short* gb=Al+aseg+(size_t)kt*4096;
    const unsigned short* gc=Wh+wseg+(size_t)kt*4096;
    const unsigned short* gd=Wl+wseg+(size_t)kt*4096;
    gload16(ga+so,      sm+lo);
    gload16(ga+2048+so, sm+2048+lo);
    gload16(gb+so,      sm+4096+lo);
    gload16(gb+2048+so, sm+6144+lo);
    gload16(gc+so,      sm+8192+lo);
    gload16(gc+2048+so, sm+10240+lo);
    gload16(gd+so,      sm+12288+lo);
    gload16(gd+2048+so, sm+14336+lo);
    __syncthreads();   // compiler drains vmcnt(0) -> data resident

    s16x8 aH[4],wH[4],tmp[4];
    #pragma unroll
    for(int i=0;i<4;i++) aH[i]=*(const s16x8*)(sm+ab+i*512);
    #pragma unroll
    for(int j=0;j<4;j++) wH[j]=*(const s16x8*)(sm+8192+wb+j*512);
    #pragma unroll
    for(int i=0;i<4;i++)
      #pragma unroll
      for(int j=0;j<4;j++)
        acc[i][j]=__builtin_amdgcn_mfma_f32_16x16x32_bf16(aH[i],wH[j],acc[i][j],0,0,0);
    #pragma unroll
    for(int j=0;j<4;j++) tmp[j]=*(const s16x8*)(sm+12288+wb+j*512);  // wL
    #pragma unroll
    for(int i=0;i<4;i++)
      #pragma unroll
      for(int j=0;j<4;j++)
        acc[i][j]=__builtin_amdgcn_mfma_f32_16x16x32_bf16(aH[i],tmp[j],acc[i][j],0,0,0);
    #pragma unroll
    for(int i=0;i<4;i++) tmp[i]=*(const s16x8*)(sm+4096+ab+i*512);   // aL
    #pragma unroll
    for(int i=0;i<4;i++)
      #pragma unroll
      for(int j=0;j<4;j++)
        acc[i][j]=__builtin_amdgcn_mfma_f32_16x16x32_bf16(tmp[i],wH[j],acc[i][j],0,0,0);
    __syncthreads();   // all reads done before next overwrite
  }

  // epilogue: row = mt*128+wr+i*16+lkg*4+r, col = nt*128+wc+j*16+lr (m89 mapping)
  int m0=mt*128, n0=nt*128;
  #pragma unroll
  for(int i=0;i<4;i++){
    #pragma unroll
    for(int r=0;r<4;r++){
      int row=m0+wr+i*16+lkg*4+r;
      #pragma unroll
      for(int j=0;j<4;j++){
        int col=n0+wc+j*16+lr;
        if(col<N){
          float v=acc[i][j][r];
          if(bias) v+=bias[col];
          if(act==1) v=siluf(v);
          if(res) v+=res[(size_t)row*N+col];
          C[(size_t)row*N+col]=v;
        }
      }
    }
  }
}

// ---------------- LayerNorm over 768, one row per block ----------------
__global__ __launch_bounds__(256) void k_ln768(const float* __restrict__ x,
    const float* __restrict__ g, const float* __restrict__ bb,
    float* __restrict__ o){
  int row=blockIdx.x, tid=threadIdx.x;
  const float* xr=x+(size_t)row*768;
  float v0=xr[tid], v1=xr[tid+256], v2=xr[tid+512];
  __shared__ float red[4];
  float m = bsum256(v0+v1+v2, red)*(1.f/768.f);
  float d0=v0-m,d1=v1-m,d2=v2-m;
  float var = bsum256(d0*d0+d1*d1+d2*d2, red)*(1.f/768.f);
  float rs=rsqrtf(var+EPSF);
  float* orow=o+(size_t)row*768;
  orow[tid]    =d0*rs*g[tid]    +bb[tid];
  orow[tid+256]=d1*rs*g[tid+256]+bb[tid+256];
  orow[tid+512]=d2*rs*g[tid+512]+bb[tid+512];
}

// ---------------- Double LayerNorm (enc then cob) ----------------
__global__ __launch_bounds__(256) void k_dblln(const float* __restrict__ x,
    const float* __restrict__ g1, const float* __restrict__ b1,
    const float* __restrict__ g2, const float* __restrict__ b2,
    float* __restrict__ o){
  int row=blockIdx.x, tid=threadIdx.x;
  const float* xr=x+(size_t)row*768;
  float v0=xr[tid], v1=xr[tid+256], v2=xr[tid+512];
  __shared__ float red[4];
  float m = bsum256(v0+v1+v2, red)*(1.f/768.f);
  float d0=v0-m,d1=v1-m,d2=v2-m;
  float var = bsum256(d0*d0+d1*d1+d2*d2, red)*(1.f/768.f);
  float rs=rsqrtf(var+EPSF);
  float x0=d0*rs*g1[tid]    +b1[tid];
  float x1=d1*rs*g1[tid+256]+b1[tid+256];
  float x2=d2*rs*g1[tid+512]+b1[tid+512];
  float m2 = bsum256(x0+x1+x2, red)*(1.f/768.f);
  float e0=x0-m2,e1=x1-m2,e2=x2-m2;
  float var2 = bsum256(e0*e0+e1*e1+e2*e2, red)*(1.f/768.f);
  float rs2=rsqrtf(var2+EPSF);
  float* orow=o+(size_t)row*768;
  orow[tid]    =e0*rs2*g2[tid]    +b2[tid];
  orow[tid+256]=e1*rs2*g2[tid+256]+b2[tid+256];
  orow[tid+512]=e2*rs2*g2[tid+512]+b2[tid+512];
}

// ---------------- causal depthwise conv (width 4) + silu ----------------
__global__ __launch_bounds__(256) void k_conv(const float* __restrict__ zx,
    const float* __restrict__ cw, const float* __restrict__ cb,
    float* __restrict__ xbc){
  int c=blockIdx.x*256+threadIdx.x;
  if(c>=1664) return;
  int t0=blockIdx.y*128, b=blockIdx.z;
  float4 w=*(const float4*)(cw+(size_t)c*4);
  float bias=cb[c];
  size_t inbase=((size_t)b*1024)*3224 + 1536 + c;
  float xm3=0.f,xm2=0.f,xm1=0.f;
  if(t0>0){
    xm3=zx[inbase+(size_t)(t0-3)*3224];
    xm2=zx[inbase+(size_t)(t0-2)*3224];
    xm1=zx[inbase+(size_t)(t0-1)*3224];
  }
  for(int i=0;i<128;i++){
    int t=t0+i;
    float xc=zx[inbase+(size_t)t*3224];
    float v=bias + w.x*xm3 + w.y*xm2 + w.z*xm1 + w.w*xc;
    xbc[((size_t)(b*1024+t))*1664 + c]=siluf(v);
    xm3=xm2; xm2=xm1; xm1=xc;
  }
}

// ---------------- dt/dA ----------------
__global__ __launch_bounds__(256) void k_dtdA(const float* __restrict__ zx,
    const float* __restrict__ dtb, const float* __restrict__ alog,
    float* __restrict__ dt_a, float* __restrict__ dA_a){
  int idx=blockIdx.x*256+threadIdx.x;
  if(idx>=98304) return;
  int row=idx/24, hh=idx-row*24;
  float v=zx[(size_t)row*3224+3200+hh]+dtb[hh];
  float dt=(v>20.f)? v : log1pf(expf(v));
  float dA=expf(-expf(alog[hh])*dt);
  dt_a[idx]=dt; dA_a[idx]=dA;
}

// ---------------- scan phase A ----------------
__global__ __launch_bounds__(64) void k_scanA(const float* __restrict__ xbc,
    const float* __restrict__ dt_a, const float* __restrict__ dA_a,
    float* __restrict__ y, float* __restrict__ Sloc, float* __restrict__ dpref){
  int blk=blockIdx.x;
  int c=blk&15, bh=blk>>4, h=bh%24, b=bh/24;
  int lane=threadIdx.x;
  float hs[64];
  #pragma unroll
  for(int n=0;n<64;n++) hs[n]=0.f;
  float pref=1.f;
  int tb=c*64;
  for(int t0=0;t0<64;t0++){
    int row=b*1024+tb+t0;
    const float* xr=xbc+(size_t)row*1664;
    float xv=xr[h*64+lane];
    float dtv=dt_a[row*24+h];
    float dAv=dA_a[row*24+h];
    float dtx=dtv*xv;
    const float* Bp=xr+1536;
    const float* Cp=xr+1600;
    float ya=0.f,yb=0.f,yc=0.f,yd=0.f;
    #pragma unroll
    for(int n=0;n<64;n+=4){
      float t0v=fmaf(dtx,Bp[n+0],hs[n+0]*dAv); hs[n+0]=t0v; ya=fmaf(t0v,Cp[n+0],ya);
      float t1v=fmaf(dtx,Bp[n+1],hs[n+1]*dAv); hs[n+1]=t1v; yb=fmaf(t1v,Cp[n+1],yb);
      float t2v=fmaf(dtx,Bp[n+2],hs[n+2]*dAv); hs[n+2]=t2v; yc=fmaf(t2v,Cp[n+2],yc);
      float t3v=fmaf(dtx,Bp[n+3],hs[n+3]*dAv); hs[n+3]=t3v; yd=fmaf(t3v,Cp[n+3],yd);
    }
    pref*=dAv;
    y[(size_t)row*1536 + h*64 + lane]=(ya+yb)+(yc+yd);
    if(lane==0) dpref[row*24+h]=pref;
  }
  float* sp=Sloc + ((size_t)blk*64 + lane)*64;
  #pragma unroll
  for(int n=0;n<64;n++) sp[n]=hs[n];
}

// ---------------- scan phase B ----------------
__global__ __launch_bounds__(256) void k_scanB(const float* __restrict__ Sloc,
    const float* __restrict__ dpref, float* __restrict__ Sin){
  int bh=blockIdx.x, tid=threadIdx.x;
  int b=bh/24, h=bh%24;
  float s[16];
  #pragma unroll
  for(int j=0;j<16;j++) s[j]=0.f;
  for(int c=0;c<16;c++){
    size_t base=((size_t)bh*16+c)*4096;
    #pragma unroll
    for(int j=0;j<16;j++) Sin[base + j*256 + tid]=s[j];
    float D=dpref[(size_t)(b*1024 + c*64 + 63)*24 + h];
    #pragma unroll
    for(int j=0;j<16;j++) s[j]=fmaf(s[j],D,Sloc[base + j*256 + tid]);
  }
}

// ---------------- scan phase C ----------------
__global__ __launch_bounds__(64) void k_scanC(const float* __restrict__ xbc,
    const float* __restrict__ Sin, const float* __restrict__ dpref,
    const float* __restrict__ Dp, float* __restrict__ y){
  int blk=blockIdx.x;
  int c=blk&15, bh=blk>>4, h=bh%24, b=bh/24;
  int lane=threadIdx.x;
  float s[64];
  const float* sp=Sin + ((size_t)blk*64 + lane)*64;
  #pragma unroll
  for(int n=0;n<64;n++) s[n]=sp[n];
  float dv=Dp[h];
  for(int t0=0;t0<64;t0++){
    int row=b*1024 + c*64 + t0;
    const float* xr=xbc+(size_t)row*1664;
    const float* Cp=xr+1600;
    float a0=0.f,a1=0.f,a2=0.f,a3=0.f;
    #pragma unroll
    for(int n=0;n<64;n+=4){
      a0=fmaf(s[n+0],Cp[n+0],a0);
      a1=fmaf(s[n+1],Cp[n+1],a1);
      a2=fmaf(s[n+2],Cp[n+2],a2);
      a3=fmaf(s[n+3],Cp[n+3],a3);
    }
    float dot=(a0+a1)+(a2+a3);
    float pref=dpref[row*24+h];
    float xv=xr[h*64+lane];
    size_t yi=(size_t)row*1536 + h*64 + lane;
    y[yi]=y[yi] + pref*dot + dv*xv;
  }
}

// ---------------- gate + RMS ----------------
__global__ __launch_bounds__(256) void k_gaterms(float* __restrict__ y,
    const float* __restrict__ zx, const float* __restrict__ w){
  int row=blockIdx.x, tid=threadIdx.x;
  const float* zr=zx+(size_t)row*3224;
  float* yr=y+(size_t)row*1536;
  float v[6]; float ss=0.f;
  #pragma unroll
  for(int j=0;j<6;j++){
    int i=tid+j*256;
    float t=yr[i]*siluf(zr[i]);
    v[j]=t; ss+=t*t;
  }
  __shared__ float red[4];
  float tot=bsum256(ss,red);
  float sc=rsqrtf(tot*(1.f/1536.f)+EPSF);
  #pragma unroll
  for(int j=0;j<6;j++){
    int i=tid+j*256;
    yr[i]=v[j]*sc*w[i];
  }
}

// ---------------- attention head scores ----------------
__global__ __launch_bounds__(768) void k_attn(const float* __restrict__ hatt,
    const float* __restrict__ wa, const float* __restrict__ ba,
    const float* __restrict__ wb, const float* __restrict__ bbv,
    const float* __restrict__ wc, const float* __restrict__ bc,
    float* __restrict__ score){
  __shared__ float hrow[8*768];
  __shared__ float red[768];
  __shared__ float rawv[8][8];
  int blk=blockIdx.x, tid=threadIdx.x;
  size_t base=(size_t)blk*8*768;
  for(int i=tid;i<6144;i+=768) hrow[i]=hatt[base+i];
  __syncthreads();
  int hh=tid/96, f=tid-hh*96;
  float aa[8], gg[8];
  float bav=ba[hh*96+f], bbx=bbv[hh*96+f];
  #pragma unroll
  for(int tt=0;tt<8;tt++){ aa[tt]=bav; gg[tt]=bbx; }
  const float* wap=wa + (size_t)hh*9216 + f;
  const float* wbp=wb + (size_t)hh*9216 + f;
  for(int e=0;e<96;e++){
    float wav=wap[(size_t)e*96];
    float wbw=wbp[(size_t)e*96];
    #pragma unroll
    for(int tt=0;tt<8;tt++){
      float hv=hrow[tt*768 + e*8 + hh];
      aa[tt]=fmaf(hv,wav,aa[tt]);
      gg[tt]=fmaf(hv,wbw,gg[tt]);
    }
  }
  float wcv=wc[hh*96+f];
  for(int tt=0;tt<8;tt++){
    float s=tanhf(aa[tt])*(1.f/(1.f+expf(-gg[tt])))*wcv;
    red[tid]=s;
    __syncthreads();
    if(tid<8){
      float sum=0.f;
      for(int i=0;i<96;i++) sum+=red[tid*96+i];
      rawv[tt][tid]=sum+bc[tid];
    }
    __syncthreads();
  }
  if(tid<8){
    float m=0.f;
    for(int h2=0;h2<8;h2++) m+=rawv[tid][h2];
    score[blk*8+tid]=m*(1.f/8.f);
  }
}

// ---------------- softmax over t per batch ----------------
__global__ __launch_bounds__(1024) void k_softmax(const float* __restrict__ score,
    float* __restrict__ A){
  int b=blockIdx.x, t=threadIdx.x, lane=t&63, w=t>>6;
  __shared__ float red[16]; __shared__ float bcast[1];
  float v=score[b*1024+t];
  float m=v;
  #pragma unroll
  for(int o=32;o;o>>=1) m=fmaxf(m,__shfl_down(m,o,64));
  if(!lane) red[w]=m;
  __syncthreads();
  if(t==0){ float mm=red[0]; for(int i=1;i<16;i++) mm=fmaxf(mm,red[i]); bcast[0]=mm; }
  __syncthreads();
  float M=bcast[0];
  float e=expf(v-M);
  float s=e;
  #pragma unroll
  for(int o=32;o;o>>=1) s+=__shfl_down(s,o,64);
  __syncthreads();
  if(!lane) red[w]=s;
  __syncthreads();
  if(t==0){ float ss=0.f; for(int i=0;i<16;i++) ss+=red[i]; bcast[0]=ss; }
  __syncthreads();
  A[b*1024+t]=e/bcast[0];
}

// ---------------- weighted pool ----------------
__global__ __launch_bounds__(256) void k_poolpart(const float* __restrict__ A,
    const float* __restrict__ x, float* __restrict__ part){
  int b=blockIdx.x, sl=blockIdx.y, tid=threadIdx.x;
  float a0=0.f,a1=0.f,a2=0.f;
  for(int i=0;i<128;i++){
    int t=sl*128+i;
    float a=A[b*1024+t];
    const float* xr=x+((size_t)(b*1024+t))*768;
    a0=fmaf(a,xr[tid],a0);
    a1=fmaf(a,xr[tid+256],a1);
    a2=fmaf(a,xr[tid+512],a2);
  }
  float* pp=part+((size_t)(b*8+sl))*768;
  pp[tid]=a0; pp[tid+256]=a1; pp[tid+512]=a2;
}

__global__ __launch_bounds__(256) void k_poolcomb(const float* __restrict__ part,
    float* __restrict__ pooled, float* __restrict__ dout_pooled){
  int b=blockIdx.x, tid=threadIdx.x;
  #pragma unroll
  for(int j=0;j<3;j++){
    int d=tid+j*256;
    float s=0.f;
    for(int sl=0;sl<8;sl++) s+=part[((size_t)(b*8+sl))*768+d];
    pooled[b*768+d]=s;
    dout_pooled[b*768+d]=s;
  }
}

// ---------------- small proj matmuls ----------------
__global__ __launch_bounds__(256) void k_proj1(const float* __restrict__ pln,
    const float* __restrict__ w1, float* __restrict__ z1p){
  int n=blockIdx.x*256+threadIdx.x;
  int ks=blockIdx.y*96;
  float a0=0.f,a1=0.f,a2=0.f,a3=0.f;
  for(int k=ks;k<ks+96;k++){
    float wv=w1[(size_t)k*3072+n];
    a0=fmaf(pln[k],wv,a0);
    a1=fmaf(pln[768+k],wv,a1);
    a2=fmaf(pln[1536+k],wv,a2);
    a3=fmaf(pln[2304+k],wv,a3);
  }
  float* zp=z1p+(size_t)blockIdx.y*4*3072;
  zp[n]=a0; zp[3072+n]=a1; zp[6144+n]=a2; zp[9216+n]=a3;
}

__global__ __launch_bounds__(256) void k_comb1(const float* __restrict__ z1p,
    const float* __restrict__ b1, float* __restrict__ z1){
  int n=blockIdx.x*256+threadIdx.x;
  #pragma unroll
  for(int r=0;r<4;r++){
    float s=0.f;
    for(int ky=0;ky<8;ky++) s+=z1p[((size_t)ky*4+r)*3072+n];
    z1[(size_t)r*3072+n]=siluf(s+b1[n]);
  }
}

__global__ __launch_bounds__(256) void k_proj2(const float* __restrict__ z1,
    const float* __restrict__ w2, float* __restrict__ fp){
  int n=blockIdx.x*256+threadIdx.x;
  int ks=blockIdx.y*256;
  float a0=0.f,a1=0.f,a2=0.f,a3=0.f;
  for(int k=ks;k<ks+256;k++){
    float wv=w2[(size_t)k*2048+n];
    a0=fmaf(z1[k],wv,a0);
    a1=fmaf(z1[3072+k],wv,a1);
    a2=fmaf(z1[6144+k],wv,a2);
    a3=fmaf(z1[9216+k],wv,a3);
  }
  float* f=fp+(size_t)blockIdx.y*4*2048;
  f[n]=a0; f[2048+n]=a1; f[4096+n]=a2; f[6144+n]=a3;
}

__global__ __launch_bounds__(256) void k_comb2(const float* __restrict__ fp,
    const float* __restrict__ b2, const float* __restrict__ g,
    const float* __restrict__ bb, const float* __restrict__ mean,
    const float* __restrict__ var, float* __restrict__ out){
  int n=blockIdx.x*256+threadIdx.x;
  #pragma unroll
  for(int r=0;r<4;r++){
    float s=0.f;
    for(int ky=0;ky<12;ky++) s+=fp[((size_t)ky*4+r)*2048+n];
    s+=b2[n];
    out[(size_t)r*2048+n]=(s-mean[n])*rsqrtf(var[n]+EPSF)*g[n]+bb[n];
  }
}

// =======================================================================
extern "C" void kernel_launch(void* const* d_in, const int* in_sizes, int n_in,
                              void* d_out, int out_size, void* d_ws, size_t ws_size,
                              hipStream_t stream){
  (void)in_sizes; (void)n_in; (void)out_size; (void)ws_size;
  const float* x        =(const float*)d_in[0];
  const float* emb_ln_g =(const float*)d_in[1];
  const float* emb_ln_b =(const float*)d_in[2];
  const float* emb_w1   =(const float*)d_in[3];
  const float* emb_b1   =(const float*)d_in[4];
  const float* emb_w2   =(const float*)d_in[5];
  const float* emb_b2   =(const float*)d_in[6];
  const float* mam_ln_g =(const float*)d_in[7];
  const float* mam_ln_b =(const float*)d_in[8];
  const float* mam_in_w =(const float*)d_in[9];
  const float* mam_conv_w=(const float*)d_in[10];
  const float* mam_conv_b=(const float*)d_in[11];
  const float* mam_dt_bias=(const float*)d_in[12];
  const float* mam_A_log=(const float*)d_in[13];
  const float* mam_D    =(const float*)d_in[14];
  const float* mam_rms_w=(const float*)d_in[15];
  const float* mam_out_w=(const float*)d_in[16];
  const float* enc_ln_g =(const float*)d_in[17];
  const float* enc_ln_b =(const float*)d_in[18];
  const float* cob_ln_g =(const float*)d_in[19];
  const float* cob_ln_b =(const float*)d_in[20];
  const float* attn_wa  =(const float*)d_in[21];
  const float* attn_ba  =(const float*)d_in[22];
  const float* attn_wb  =(const float*)d_in[23];
  const float* attn_bb  =(const float*)d_in[24];
  const float* attn_wc  =(const float*)d_in[25];
  const float* attn_bc  =(const float*)d_in[26];
  const float* proj_ln_g=(const float*)d_in[27];
  const float* proj_ln_b=(const float*)d_in[28];
  const float* proj_w1  =(const float*)d_in[29];
  const float* proj_b1  =(const float*)d_in[30];
  const float* proj_w2  =(const float*)d_in[31];
  const float* proj_b2  =(const float*)d_in[32];
  const float* bn_g     =(const float*)d_in[33];
  const float* bn_b     =(const float*)d_in[34];
  const float* bn_mean  =(const float*)d_in[35];
  const float* bn_var   =(const float*)d_in[36];
  float* out=(float*)d_out;

  float* Wp=(float*)d_ws;
  size_t off=0;
  auto alloc=[&](size_t n){ float* p=Wp+off; off+=n; return p; };
  float* h    =alloc(3145728);   // 4096x768
  float* hn   =alloc(3145728);
  float* zx   =alloc(13205504);  // 4096x3224
  float* xbc  =alloc(6815744);   // 4096x1664
  float* y    =alloc(6291456);   // 4096x1536
  float* Sloc =alloc(6291456);   // scan-local states; ALIASED as A-split bufs
  float* Sin  =alloc(6291456);   // inter-chunk states; ALIASED as W-split bufs
  float* dt_a =alloc(98304);
  float* dA_a =alloc(98304);
  float* dpref=alloc(98304);
  float* score=alloc(4096);
  float* Aw   =alloc(4096);
  float* part =alloc(24576);
  float* pooled=alloc(3072);
  float* pln  =alloc(3072);
  float* z1p  =alloc(98304);
  float* z1   =alloc(12288);
  float* fp   =alloc(98304);
  float* t1=y;

  // Split-buffer aliases (time-disjoint with the scan's use of Sloc/Sin:
  // per-layer order is in_proj GEMM -> scanA/B/C -> out_proj GEMM).
  unsigned short* Ah=(unsigned short*)Sloc;                 // up to 4096x1536 shorts
  unsigned short* Al=(unsigned short*)(Sloc+3145728);
  unsigned short* Whs=(unsigned short*)Sin;                 // up to 768x3328 shorts
  unsigned short* Wls=(unsigned short*)(Sin+3145728);

  // GEMM driver: A[M=4096,K] @ W[K,N] with Kt=K/32, Nt=ceil(N/128)
  auto gemm=[&](const float* A, const float* W, const float* bias,
                const float* res, float* C, int N, int K, int act){
    int Kt=K/32, Nt=(N+127)/128;
    k_splitA<<<4096*K/2048,256,0,stream>>>(A, Ah, Al, K, Kt);
    k_splitW<<<Nt*Kt*2,256,0,stream>>>(W, Whs, Wls, N, Kt);
    k_gemm2<<<dim3(32,Nt),256,0,stream>>>(Ah, Al, Whs, Wls, bias, res, C, N, Kt, act);
  };

  // ---- embedding MLP ----
  k_ln768<<<4096,256,0,stream>>>(x, emb_ln_g, emb_ln_b, hn);
  gemm(hn, emb_w1, emb_b1, nullptr, t1, 768, 768, 1);
  gemm(t1, emb_w2, emb_b2, nullptr, h, 768, 768, 0);

  // ---- 4 mamba2 layers ----
  for(int l=0;l<4;l++){
    k_ln768<<<4096,256,0,stream>>>(h, mam_ln_g+(size_t)l*768, mam_ln_b+(size_t)l*768, hn);
    gemm(hn, mam_in_w+(size_t)l*768*3224, nullptr, nullptr, zx, 3224, 768, 0);
    k_conv<<<dim3(7,8,4),256,0,stream>>>(zx, mam_conv_w+(size_t)l*1664*4, mam_conv_b+(size_t)l*1664, xbc);
    k_dtdA<<<384,256,0,stream>>>(zx, mam_dt_bias+(size_t)l*24, mam_A_log+(size_t)l*24, dt_a, dA_a);
    k_scanA<<<1536,64,0,stream>>>(xbc, dt_a, dA_a, y, Sloc, dpref);
    k_scanB<<<96,256,0,stream>>>(Sloc, dpref, Sin);
    k_scanC<<<1536,64,0,stream>>>(xbc, Sin, dpref, mam_D+(size_t)l*24, y);
    k_gaterms<<<4096,256,0,stream>>>(y, zx, mam_rms_w+(size_t)l*1536);
    gemm(y, mam_out_w+(size_t)l*1536*768, nullptr, h, h, 768, 1536, 0);
  }

  // ---- head ----
  k_dblln<<<4096,256,0,stream>>>(h, enc_ln_g,enc_ln_b, cob_ln_g,cob_ln_b, hn);
  k_attn<<<512,768,0,stream>>>(hn, attn_wa,attn_ba,attn_wb,attn_bb,attn_wc,attn_bc, score);
  k_softmax<<<4,1024,0,stream>>>(score, Aw);
  k_poolpart<<<dim3(4,8),256,0,stream>>>(Aw, x, part);
  k_poolcomb<<<4,256,0,stream>>>(part, pooled, out+8192);
  k_ln768<<<4,256,0,stream>>>(pooled, proj_ln_g, proj_ln_b, pln);
  k_proj1<<<dim3(12,8),256,0,stream>>>(pln, proj_w1, z1p);
  k_comb1<<<12,256,0,stream>>>(z1p, proj_b1, z1);
  k_proj2<<<dim3(8,12),256,0,stream>>>(z1, proj_w2, fp);
  k_comb2<<<8,256,0,stream>>>(fp, proj_b2, bn_g, bn_b, bn_mean, bn_var, out);
}